// Round 3
// baseline (26349.750 us; speedup 1.0000x reference)
//
#include <hip/hip_runtime.h>

#define T_STEPS 512
#define BATCH   64
#define HID     1024
#define GDIM    4096   // 4*H gate columns
#define NWG     256    // persistent workgroups (1 per CU)
#define LDW     1032   // LDS row stride in shorts (1024 + 8 pad -> 2-way conflicts only)

using short8  = __attribute__((ext_vector_type(8))) short;
using floatx4 = __attribute__((ext_vector_type(4))) float;

__device__ inline unsigned short bf16_rne(float f) {
  union { float f; unsigned u; } x; x.f = f;
  unsigned r = x.u + 0x7FFFu + ((x.u >> 16) & 1u);
  return (unsigned short)(r >> 16);
}

__device__ inline float sigmoid_(float x) { return 1.0f / (1.0f + __expf(-x)); }
__device__ inline float tanh_(float x) {
  float e = __expf(-2.0f * fabsf(x));
  float r = (1.0f - e) / (1.0f + e);
  return copysignf(r, x);
}

#define LOAD4(dst, ptr) { float4 _t4 = *(const float4*)(ptr); \
  dst[0]=_t4.x; dst[1]=_t4.y; dst[2]=_t4.z; dst[3]=_t4.w; }

struct Params {
  const float* input; const float* hidden; const float* cell;
  const float* w_ih;  const float* w_hh;   const float* w_ch;
  const float* bias;
  const float* gamma_f; const float* gamma_i; const float* gamma_g;
  const float* gamma_o; const float* gamma_c; const float* beta_c;
  float* out;
  unsigned short* wx;    // bf16 W_ih [4096][1024]
  float* gates;          // [64][4096]
  float* c_ws;           // [64][1024]
  unsigned short* hbf;   // bf16 h [64][1024]
  unsigned short* xbf;   // bf16 x_t [64][1024]
  unsigned* bar;
};

// ---------------------------------------------------------------------------
// grid barrier: monotonic counter, one arrival per wg, device-scope fences.
// ---------------------------------------------------------------------------
__device__ inline void gbar(unsigned* bar, unsigned target) {
  __syncthreads();                      // all wg mem-ops drained (s_waitcnt before s_barrier)
  if (threadIdx.x == 0) {
    __threadfence();                    // release: flush this CU/XCD caches
    __hip_atomic_fetch_add(bar, 1u, __ATOMIC_RELAXED, __HIP_MEMORY_SCOPE_AGENT);
    while (__hip_atomic_load(bar, __ATOMIC_RELAXED, __HIP_MEMORY_SCOPE_AGENT) < target)
      __builtin_amdgcn_s_sleep(2);
    __threadfence();                    // acquire: invalidate stale L1/L2
  }
  __syncthreads();
}

// ---------------------------------------------------------------------------
// block reduce: sum N accumulators across 256 threads (4 waves of 64)
// ---------------------------------------------------------------------------
template<int N>
__device__ inline void block_reduce(float* v, float* red, int tid) {
#pragma unroll
  for (int i = 0; i < N; ++i) {
    float x = v[i];
#pragma unroll
    for (int off = 32; off > 0; off >>= 1)
      x += __shfl_xor(x, off, 64);
    v[i] = x;
  }
  const int wave = tid >> 6;
  if ((tid & 63) == 0) {
#pragma unroll
    for (int i = 0; i < N; ++i) red[wave * N + i] = v[i];
  }
  __syncthreads();
#pragma unroll
  for (int i = 0; i < N; ++i)
    v[i] = red[i] + red[N + i] + red[2 * N + i] + red[3 * N + i];
}

// ---------------------------------------------------------------------------
// LN + gate pointwise for batch row b (one wg, 256 threads, 4 elems/thread)
// ---------------------------------------------------------------------------
__device__ inline void pointwise(const Params& p, int b, int t, int tid, float* sm) {
  const int j = tid * 4;
  const float* grow = p.gates + (size_t)b * GDIM;
  float* hout = p.out + (size_t)t * BATCH * HID;

  float fh[4], ih[4], gh[4], oh[4], cc[4], wcf[4], wci[4], wco[4];
  LOAD4(fh, grow + j);
  LOAD4(ih, grow + HID + j);
  LOAD4(gh, grow + 2 * HID + j);
  LOAD4(oh, grow + 3 * HID + j);
  LOAD4(cc, p.c_ws + (size_t)b * HID + j);
  LOAD4(wcf, p.w_ch + j);
  LOAD4(wci, p.w_ch + HID + j);
  LOAD4(wco, p.w_ch + 2 * HID + j);

  float af[4], ai[4], ag[4];
  float s[6] = {0, 0, 0, 0, 0, 0};
#pragma unroll
  for (int r = 0; r < 4; ++r) {
    af[r] = fh[r] + wcf[r] * cc[r];
    ai[r] = ih[r] + wci[r] * cc[r];
    ag[r] = gh[r];
    s[0] += af[r]; s[1] += af[r] * af[r];
    s[2] += ai[r]; s[3] += ai[r] * ai[r];
    s[4] += ag[r]; s[5] += ag[r] * ag[r];
  }
  block_reduce<6>(s, sm, tid);
  const float invH = 1.0f / (float)HID;
  float mu_f = s[0] * invH, is_f = rsqrtf(s[1] * invH - mu_f * mu_f + 1e-5f);
  float mu_i = s[2] * invH, is_i = rsqrtf(s[3] * invH - mu_i * mu_i + 1e-5f);
  float mu_g = s[4] * invH, is_g = rsqrtf(s[5] * invH - mu_g * mu_g + 1e-5f);

  float gf4[4], gi4[4], gg4[4], bf4[4], bi4[4], bg4[4];
  LOAD4(gf4, p.gamma_f + j); LOAD4(gi4, p.gamma_i + j); LOAD4(gg4, p.gamma_g + j);
  LOAD4(bf4, p.bias + j);    LOAD4(bi4, p.bias + HID + j); LOAD4(bg4, p.bias + 2 * HID + j);

  float cn[4], ao[4];
  float s2[4] = {0, 0, 0, 0};
#pragma unroll
  for (int r = 0; r < 4; ++r) {
    float f = sigmoid_((af[r] - mu_f) * is_f * gf4[r] + bf4[r]);
    float i = sigmoid_((ai[r] - mu_i) * is_i * gi4[r] + bi4[r]);
    float g = tanh_((ag[r] - mu_g) * is_g * gg4[r] + bg4[r]);
    cn[r] = f * cc[r] + i * g;
    ao[r] = oh[r] + wco[r] * cn[r];
    s2[0] += cn[r]; s2[1] += cn[r] * cn[r];
    s2[2] += ao[r]; s2[3] += ao[r] * ao[r];
  }
  { float4 v; v.x = cn[0]; v.y = cn[1]; v.z = cn[2]; v.w = cn[3];
    *(float4*)(p.c_ws + (size_t)b * HID + j) = v; }

  block_reduce<4>(s2, sm + 24, tid);
  float mu_c = s2[0] * invH, is_c = rsqrtf(s2[1] * invH - mu_c * mu_c + 1e-5f);
  float mu_o = s2[2] * invH, is_o = rsqrtf(s2[3] * invH - mu_o * mu_o + 1e-5f);

  float gc4[4], bc4[4], go4[4], bo4[4];
  LOAD4(gc4, p.gamma_c + j); LOAD4(bc4, p.beta_c + j);
  LOAD4(go4, p.gamma_o + j); LOAD4(bo4, p.bias + 3 * HID + j);

  float h4[4];
#pragma unroll
  for (int r = 0; r < 4; ++r) {
    float cl = (cn[r] - mu_c) * is_c * gc4[r] + bc4[r];
    float o  = sigmoid_((ao[r] - mu_o) * is_o * go4[r] + bo4[r]);
    h4[r] = o * tanh_(cl);
  }
  { float4 v; v.x = h4[0]; v.y = h4[1]; v.z = h4[2]; v.w = h4[3];
    *(float4*)(hout + (size_t)b * HID + j) = v; }
  { ushort4 hv;
    hv.x = bf16_rne(h4[0]); hv.y = bf16_rne(h4[1]);
    hv.z = bf16_rne(h4[2]); hv.w = bf16_rne(h4[3]);
    *(ushort4*)(p.hbf + (size_t)b * HID + j) = hv; }

  if (t == T_STEPS - 1) {   // h_f and c_f tails of d_out
    const size_t OUT0 = (size_t)T_STEPS * BATCH * HID;
    float4 v; v.x = h4[0]; v.y = h4[1]; v.z = h4[2]; v.w = h4[3];
    *(float4*)(p.out + OUT0 + (size_t)b * HID + j) = v;
    float4 w; w.x = cn[0]; w.y = cn[1]; w.z = cn[2]; w.w = cn[3];
    *(float4*)(p.out + OUT0 + (size_t)BATCH * HID + (size_t)b * HID + j) = w;
  }
}

// ---------------------------------------------------------------------------
// Persistent kernel: all 512 steps, 2 grid barriers per step.
// wg owns gate cols [wg*16, wg*16+16): W_hh slice in LDS, W_ih slice in L2.
// ---------------------------------------------------------------------------
__global__ __launch_bounds__(256) void lstm_kernel(Params p)
{
  __shared__ __align__(16) unsigned short Wlds[16 * LDW];
  __shared__ float sm[40];
  const int wg   = blockIdx.x;
  const int tid  = threadIdx.x;
  const int wave = tid >> 6;
  const int lane = tid & 63;
  const int quad = lane >> 4;
  const int l16  = lane & 15;

  // ---- setup: pack W_hh rows -> LDS (bf16), W_ih rows -> global wx (bf16) ----
  {
    const size_t rb = (size_t)wg * 16;
#pragma unroll
    for (int i = 0; i < 16; ++i) {
      int e = (tid + i * 256) * 4;          // elem 0..16383 of the 16x1024 slice
      int r = e >> 10, c = e & 1023;
      float4 vh = *(const float4*)(p.w_hh + (rb + r) * 1024 + c);
      ushort4 uh;
      uh.x = bf16_rne(vh.x); uh.y = bf16_rne(vh.y);
      uh.z = bf16_rne(vh.z); uh.w = bf16_rne(vh.w);
      *(ushort4*)(&Wlds[r * LDW + c]) = uh;
      float4 vx = *(const float4*)(p.w_ih + (rb + r) * 1024 + c);
      ushort4 ux;
      ux.x = bf16_rne(vx.x); ux.y = bf16_rne(vx.y);
      ux.z = bf16_rne(vx.z); ux.w = bf16_rne(vx.w);
      *(ushort4*)(p.wx + (rb + r) * 1024 + c) = ux;
    }
  }
  if (wg < BATCH) {       // init h0, x0 (bf16) and c
    int j = tid * 4;
    size_t off = (size_t)wg * HID + j;
    float4 h = *(const float4*)(p.hidden + off);
    float4 x = *(const float4*)(p.input + off);
    float4 c = *(const float4*)(p.cell + off);
    ushort4 hv, xv;
    hv.x = bf16_rne(h.x); hv.y = bf16_rne(h.y); hv.z = bf16_rne(h.z); hv.w = bf16_rne(h.w);
    xv.x = bf16_rne(x.x); xv.y = bf16_rne(x.y); xv.z = bf16_rne(x.z); xv.w = bf16_rne(x.w);
    *(ushort4*)(p.hbf + off) = hv;
    *(ushort4*)(p.xbf + off) = xv;
    *(float4*)(p.c_ws + off) = c;
  }
  unsigned bt = 0;
  gbar(p.bar, ++bt * NWG);

  // persistent GEMM addressing (m89-verified 16x16x32 fragment layouts)
  const int n = wg * 16 + l16;                              // gate col / W row
  const unsigned short* wl   = &Wlds[l16 * LDW + quad * 8]; // B h-part (LDS)
  const unsigned short* bx   = p.wx  + (size_t)n * 1024 + quad * 8;  // B x-part
  const unsigned short* arow = p.hbf + (size_t)(wave * 16 + l16) * HID + quad * 8;
  const unsigned short* xrow = p.xbf + (size_t)(wave * 16 + l16) * HID + quad * 8;

  for (int t = 0; t < T_STEPS; ++t) {
    floatx4 a0 = {0,0,0,0}, a1 = {0,0,0,0}, a2 = {0,0,0,0}, a3 = {0,0,0,0};
    // h half: A from global hbf, B from LDS — 4 acc chains
#pragma unroll 2
    for (int kc = 0; kc < 32; kc += 4) {
      short8 af0 = *(const short8*)(arow + (kc + 0) * 32);
      short8 bf0 = *(const short8*)(wl   + (kc + 0) * 32);
      short8 af1 = *(const short8*)(arow + (kc + 1) * 32);
      short8 bf1 = *(const short8*)(wl   + (kc + 1) * 32);
      short8 af2 = *(const short8*)(arow + (kc + 2) * 32);
      short8 bf2 = *(const short8*)(wl   + (kc + 2) * 32);
      short8 af3 = *(const short8*)(arow + (kc + 3) * 32);
      short8 bf3 = *(const short8*)(wl   + (kc + 3) * 32);
      a0 = __builtin_amdgcn_mfma_f32_16x16x32_bf16(af0, bf0, a0, 0, 0, 0);
      a1 = __builtin_amdgcn_mfma_f32_16x16x32_bf16(af1, bf1, a1, 0, 0, 0);
      a2 = __builtin_amdgcn_mfma_f32_16x16x32_bf16(af2, bf2, a2, 0, 0, 0);
      a3 = __builtin_amdgcn_mfma_f32_16x16x32_bf16(af3, bf3, a3, 0, 0, 0);
    }
    // x half: A from global xbf, B from L2-resident wx
#pragma unroll 2
    for (int kc = 0; kc < 32; kc += 4) {
      short8 af0 = *(const short8*)(xrow + (kc + 0) * 32);
      short8 bf0 = *(const short8*)(bx   + (kc + 0) * 32);
      short8 af1 = *(const short8*)(xrow + (kc + 1) * 32);
      short8 bf1 = *(const short8*)(bx   + (kc + 1) * 32);
      short8 af2 = *(const short8*)(xrow + (kc + 2) * 32);
      short8 bf2 = *(const short8*)(bx   + (kc + 2) * 32);
      short8 af3 = *(const short8*)(xrow + (kc + 3) * 32);
      short8 bf3 = *(const short8*)(bx   + (kc + 3) * 32);
      a0 = __builtin_amdgcn_mfma_f32_16x16x32_bf16(af0, bf0, a0, 0, 0, 0);
      a1 = __builtin_amdgcn_mfma_f32_16x16x32_bf16(af1, bf1, a1, 0, 0, 0);
      a2 = __builtin_amdgcn_mfma_f32_16x16x32_bf16(af2, bf2, a2, 0, 0, 0);
      a3 = __builtin_amdgcn_mfma_f32_16x16x32_bf16(af3, bf3, a3, 0, 0, 0);
    }
    floatx4 acc = (a0 + a1) + (a2 + a3);

    // C/D layout (m89-verified): col = lane&15, row = quad*4 + reg
#pragma unroll
    for (int r = 0; r < 4; ++r) {
      int m = wave * 16 + quad * 4 + r;
      p.gates[(size_t)m * GDIM + n] = acc[r];
    }
    gbar(p.bar, ++bt * NWG);

    if (wg < BATCH) {
      pointwise(p, wg, t, tid, sm);
    } else if (wg < 2 * BATCH && t + 1 < T_STEPS) {
      // wgs 64..127: convert x_{t+1} row (wg-64) -> bf16 in parallel
      int b = wg - BATCH, j = tid * 4;
      float4 xv = *(const float4*)(p.input + ((size_t)(t + 1) * BATCH + b) * HID + j);
      ushort4 xb;
      xb.x = bf16_rne(xv.x); xb.y = bf16_rne(xv.y);
      xb.z = bf16_rne(xv.z); xb.w = bf16_rne(xv.w);
      *(ushort4*)(p.xbf + (size_t)b * HID + j) = xb;
    }
    gbar(p.bar, ++bt * NWG);
  }
}

// ---------------------------------------------------------------------------
extern "C" void kernel_launch(void* const* d_in, const int* in_sizes, int n_in,
                              void* d_out, int out_size, void* d_ws, size_t ws_size,
                              hipStream_t stream) {
  (void)in_sizes; (void)n_in; (void)out_size; (void)ws_size;

  // ws layout: [ wx bf16 8MB | gates 1MB | c 256KB | hbf 128KB | xbf 128KB | bar ]
  unsigned short* wx = (unsigned short*)d_ws;
  float* gates = (float*)((char*)d_ws + (size_t)GDIM * 1024 * sizeof(unsigned short));
  float* c_ws  = gates + (size_t)BATCH * GDIM;
  unsigned short* hbf = (unsigned short*)(c_ws + BATCH * HID);
  unsigned short* xbf = hbf + BATCH * HID;
  unsigned* bar = (unsigned*)(xbf + BATCH * HID);

  hipMemsetAsync(bar, 0, sizeof(unsigned), stream);

  Params p;
  p.input   = (const float*)d_in[0];
  p.hidden  = (const float*)d_in[1];
  p.cell    = (const float*)d_in[2];
  p.w_ih    = (const float*)d_in[3];
  p.w_hh    = (const float*)d_in[4];
  p.w_ch    = (const float*)d_in[5];
  p.bias    = (const float*)d_in[6];
  p.gamma_f = (const float*)d_in[7];
  p.gamma_i = (const float*)d_in[8];
  p.gamma_g = (const float*)d_in[9];
  p.gamma_o = (const float*)d_in[10];
  p.gamma_c = (const float*)d_in[11];
  p.beta_c  = (const float*)d_in[12];
  p.out = (float*)d_out;
  p.wx = wx; p.gates = gates; p.c_ws = c_ws; p.hbf = hbf; p.xbf = xbf; p.bar = bar;

  void* args[] = { &p };
  hipLaunchCooperativeKernel((const void*)lstm_kernel, dim3(NWG), dim3(256),
                             args, 0, stream);
}